// Round 1
// baseline (2955.710 us; speedup 1.0000x reference)
//
#include <hip/hip_runtime.h>

#define Bn 8
#define Nn 8192
#define Cn 64
#define Mn 2048
#define Kn 16
#define FPS_T 1024
#define PPT (Nn / FPS_T)   // 8

// ---------------------------------------------------------------------------
// FPS: one block per batch. d2 + coords in registers. Exact argmax semantics:
// max-value reduce, then equality scan + atomicMin for first-index tie-break.
// Distance arithmetic mirrors XLA: squares then left-to-right adds, no FMA.
// ---------------------------------------------------------------------------
__global__ __launch_bounds__(FPS_T) void fps_kernel(
    const float* __restrict__ p1,
    float* __restrict__ out_p2,
    float* __restrict__ out_idxf)
{
    const int b = blockIdx.x;
    const int t = threadIdx.x;
    const float* __restrict__ P = p1 + (size_t)b * (Nn * 3);

    float px[PPT], py[PPT], pz[PPT], d2[PPT];
#pragma unroll
    for (int j = 0; j < PPT; ++j) {
        const int g = t + j * FPS_T;
        px[j] = P[g * 3 + 0];
        py[j] = P[g * 3 + 1];
        pz[j] = P[g * 3 + 2];
        d2[j] = __int_as_float(0x7f800000);  // +inf
    }

    __shared__ float s_vals[16];
    __shared__ float s_last[2][3];
    __shared__ int   s_bi[2];

    if (t == 0) {
        s_last[1][0] = P[0]; s_last[1][1] = P[1]; s_last[1][2] = P[2];
        s_bi[0] = 0x7fffffff; s_bi[1] = 0x7fffffff;
        out_idxf[(size_t)b * Mn] = 0.0f;
        float* o = out_p2 + (size_t)b * Mn * 3;
        o[0] = P[0]; o[1] = P[1]; o[2] = P[2];
    }
    __syncthreads();
    float qx = s_last[1][0], qy = s_last[1][1], qz = s_last[1][2];

    for (int m = 1; m < Mn; ++m) {
        // ---- distance update + local max (value only) ----
        float lm = -1.0f;
#pragma unroll
        for (int j = 0; j < PPT; ++j) {
            const float dx = __fsub_rn(px[j], qx);
            const float dy = __fsub_rn(py[j], qy);
            const float dz = __fsub_rn(pz[j], qz);
            const float dist = __fadd_rn(
                __fadd_rn(__fmul_rn(dx, dx), __fmul_rn(dy, dy)),
                __fmul_rn(dz, dz));
            const float nd = fminf(d2[j], dist);
            d2[j] = nd;
            lm = fmaxf(lm, nd);
        }
        // ---- wave max ----
#pragma unroll
        for (int off = 32; off >= 1; off >>= 1)
            lm = fmaxf(lm, __shfl_down(lm, off));
        if ((t & 63) == 0) s_vals[t >> 6] = lm;
        __syncthreads();                       // SYNC1
        // ---- block max: every 16-lane group reduces the 16 wave maxima ----
        float V = s_vals[t & 15];
#pragma unroll
        for (int msk = 1; msk < 16; msk <<= 1)
            V = fmaxf(V, __shfl_xor(V, msk));
        // ---- first index achieving V ----
        int cand = 0x7fffffff;
#pragma unroll
        for (int j = PPT - 1; j >= 0; --j)
            if (d2[j] == V) cand = t + j * FPS_T;   // descending j: keeps smallest g
        if (cand != 0x7fffffff) atomicMin(&s_bi[m & 1], cand);
        if (t == 0) s_bi[(m + 1) & 1] = 0x7fffffff;   // reset other buffer
        __syncthreads();                       // SYNC2
        const int bi = s_bi[m & 1];
        if (t == (bi & (FPS_T - 1))) {
            const int jj = bi >> 10;
            float cx = px[0], cy = py[0], cz = pz[0];
#pragma unroll
            for (int j = 1; j < PPT; ++j) {
                const bool c = (jj == j);
                cx = c ? px[j] : cx;
                cy = c ? py[j] : cy;
                cz = c ? pz[j] : cz;
            }
            const int nb = (m + 1) & 1;
            s_last[nb][0] = cx; s_last[nb][1] = cy; s_last[nb][2] = cz;
            out_idxf[(size_t)b * Mn + m] = (float)bi;
            float* o = out_p2 + ((size_t)b * Mn + m) * 3;
            o[0] = cx; o[1] = cy; o[2] = cz;
        }
        __syncthreads();                       // SYNC3
        const int nb = (m + 1) & 1;
        qx = s_last[nb][0]; qy = s_last[nb][1]; qz = s_last[nb][2];
    }
}

// ---------------------------------------------------------------------------
// kNN + feature mean: one wave per query. Wave-distributed sorted top-16
// (slot s lives on lane s, lex order (d2, idx)). d2 mirrors the reference's
// |q|^2 + |p|^2 - 2*dot expansion (FMA-chain dot, K=3 GEMM-style).
// ---------------------------------------------------------------------------
#define KNN_WPB 4
__global__ __launch_bounds__(64 * KNN_WPB) void knn_mean_kernel(
    const float* __restrict__ p1,
    const float* __restrict__ x,
    const float* __restrict__ p2,
    float* __restrict__ y)
{
    const int lane = threadIdx.x & 63;
    const int wid  = threadIdx.x >> 6;
    const int q    = blockIdx.x * KNN_WPB + wid;    // 0 .. B*M-1
    const int b    = q >> 11;                        // q / Mn  (Mn = 2048)
    const float* __restrict__ P = p1 + (size_t)b * (Nn * 3);

    const float qx = p2[(size_t)q * 3 + 0];
    const float qy = p2[(size_t)q * 3 + 1];
    const float qz = p2[(size_t)q * 3 + 2];
    const float qq = __fadd_rn(
        __fadd_rn(__fmul_rn(qx, qx), __fmul_rn(qy, qy)), __fmul_rn(qz, qz));

    float slotv = __int_as_float(0x7f800000);
    int   sloti = 0x7fffffff;
    float thr   = __int_as_float(0x7f800000);
    int   thri  = 0x7fffffff;

    for (int c = 0; c < Nn / 64; ++c) {
        const int g = c * 64 + lane;
        const float ax = P[g * 3 + 0];
        const float ay = P[g * 3 + 1];
        const float az = P[g * 3 + 2];
        const float pp = __fadd_rn(
            __fadd_rn(__fmul_rn(ax, ax), __fmul_rn(ay, ay)), __fmul_rn(az, az));
        const float dot = __fmaf_rn(az, qz, __fmaf_rn(ay, qy, __fmul_rn(ax, qx)));
        const float d = __fsub_rn(__fadd_rn(qq, pp), __fmul_rn(2.0f, dot));
        const bool pass = (d < thr) || (d == thr && g < thri);
        unsigned long long ball = __ballot(pass);
        while (ball) {
            const int src = __builtin_ctzll(ball);
            ball &= ball - 1ull;
            const float v  = __shfl(d, src);
            const int   vi = __shfl(g, src);
            const float upv = __shfl_up(slotv, 1);
            const int   upi = __shfl_up(sloti, 1);
            const bool beforeme = (v < slotv) || (v == slotv && vi < sloti);
            bool beforeup = (v < upv) || (v == upv && vi < upi);
            if (lane == 0) beforeup = false;
            if (beforeme) {
                slotv = beforeup ? upv : v;
                sloti = beforeup ? upi : vi;
            }
            thr  = __shfl(slotv, 15);
            thri = __shfl(sloti, 15);
        }
    }

    // ---- feature mean over the 16 neighbors (ascending d2 order) ----
    float acc = 0.0f;
    const float* __restrict__ xb = x + (size_t)b * Nn * Cn;
#pragma unroll
    for (int s = 0; s < Kn; ++s) {
        const int ni = __shfl(sloti, s);
        acc = __fadd_rn(acc, xb[(size_t)ni * Cn + lane]);   // lane == channel (Cn==64)
    }
    y[(size_t)q * Cn + lane] = __fmul_rn(acc, 0.0625f);
}

// ---------------------------------------------------------------------------
extern "C" void kernel_launch(void* const* d_in, const int* in_sizes, int n_in,
                              void* d_out, int out_size, void* d_ws, size_t ws_size,
                              hipStream_t stream) {
    const float* p1 = (const float*)d_in[0];
    const float* x  = (const float*)d_in[1];
    // d_in[2] = stride (4), d_in[3] = num_neighbors (16) — fixed by setup.

    float* y    = (float*)d_out;                       // (B, M, C)
    float* p2   = y    + (size_t)Bn * Mn * Cn;         // (B, M, 3)
    float* idxf = p2   + (size_t)Bn * Mn * 3;          // (B, M) as float

    fps_kernel<<<Bn, FPS_T, 0, stream>>>(p1, p2, idxf);
    knn_mean_kernel<<<(Bn * Mn) / KNN_WPB, 64 * KNN_WPB, 0, stream>>>(p1, x, p2, y);
}

// Round 4
// 2121.607 us; speedup vs baseline: 1.3931x; 1.3931x over previous
//
#include <hip/hip_runtime.h>

#define Bn 8
#define Nn 8192
#define Cn 64
#define Mn 2048
#define Kn 16
#define FPS_T 512
#define PPT (Nn / FPS_T)   // 16

// ---- DPP wave-64 reductions (rocPRIM gfx9 pattern), result valid in lane 63.
template <int CTRL, int RMASK>
__device__ __forceinline__ float dpp_max_step(float v) {
    int mv = __builtin_amdgcn_update_dpp(__float_as_int(v), __float_as_int(v),
                                         CTRL, RMASK, 0xF, false);
    return fmaxf(v, __int_as_float(mv));
}
template <int CTRL, int RMASK>
__device__ __forceinline__ unsigned dpp_min_step(unsigned v) {
    unsigned mv = (unsigned)__builtin_amdgcn_update_dpp((int)v, (int)v,
                                                        CTRL, RMASK, 0xF, false);
    return (mv < v) ? mv : v;
}
__device__ __forceinline__ float wave_max_f32(float v) {
    v = dpp_max_step<0x111, 0xF>(v);   // row_shr:1
    v = dpp_max_step<0x112, 0xF>(v);   // row_shr:2
    v = dpp_max_step<0x114, 0xF>(v);   // row_shr:4
    v = dpp_max_step<0x118, 0xF>(v);   // row_shr:8
    v = dpp_max_step<0x142, 0xA>(v);   // row_bcast:15 (write rows 1,3)
    v = dpp_max_step<0x143, 0xC>(v);   // row_bcast:31 (write rows 2,3)
    return v;                           // lane 63 holds the wave max
}
__device__ __forceinline__ unsigned wave_min_u32(unsigned v) {
    v = dpp_min_step<0x111, 0xF>(v);
    v = dpp_min_step<0x112, 0xF>(v);
    v = dpp_min_step<0x114, 0xF>(v);
    v = dpp_min_step<0x118, 0xF>(v);
    v = dpp_min_step<0x142, 0xA>(v);
    v = dpp_min_step<0x143, 0xC>(v);
    return v;                           // lane 63 holds the wave min
}

// ---------------------------------------------------------------------------
// FPS: one block/batch, 512 threads, 16 pts/thread in registers. One barrier
// per iteration. Cross-wave argmax via packed (valbits<<32 | ~idx) u64
// atomicMax into a triple-buffered LDS slot. All coords staged SoA in LDS;
// outputs staged in LDS and flushed once. Distance arithmetic bit-identical
// to the XLA reference (separate mul/add, no FMA), first-index tie-break.
// ---------------------------------------------------------------------------
__global__ __launch_bounds__(FPS_T) void fps_kernel(
    const float* __restrict__ p1,
    float* __restrict__ out_p2,
    float* __restrict__ out_idxf)
{
    __shared__ float s_Px[Nn], s_Py[Nn], s_Pz[Nn];      // 96 KB
    __shared__ unsigned long long s_key[3];
    __shared__ int s_oidx[Mn];                           // 8 KB

    const int b = blockIdx.x;
    const int t = threadIdx.x;
    const float* __restrict__ P = p1 + (size_t)b * (Nn * 3);

    float px[PPT], py[PPT], pz[PPT], d2[PPT];
#pragma unroll
    for (int j = 0; j < PPT; ++j) {
        const int g = t + j * FPS_T;
        const float x = P[g * 3 + 0];
        const float y = P[g * 3 + 1];
        const float z = P[g * 3 + 2];
        px[j] = x; py[j] = y; pz[j] = z;
        s_Px[g] = x; s_Py[g] = y; s_Pz[g] = z;
        d2[j] = __int_as_float(0x7f800000);   // +inf
    }
    if (t < 3) s_key[t] = 0ull;
    if (t == 0) s_oidx[0] = 0;
    __syncthreads();

    float qx = s_Px[0], qy = s_Py[0], qz = s_Pz[0];

    for (int m = 1; m < Mn; ++m) {
        // ---- exact distance update + per-thread max (value only) ----
        float lm = -1.0f;
#pragma unroll
        for (int j = 0; j < PPT; ++j) {
            const float dx = __fsub_rn(px[j], qx);
            const float dy = __fsub_rn(py[j], qy);
            const float dz = __fsub_rn(pz[j], qz);
            const float dist = __fadd_rn(
                __fadd_rn(__fmul_rn(dx, dx), __fmul_rn(dy, dy)),
                __fmul_rn(dz, dz));
            const float nd = fminf(d2[j], dist);
            d2[j] = nd;
            lm = fmaxf(lm, nd);
        }
        // ---- wave max value ----
        lm = wave_max_f32(lm);
        const float V = __int_as_float(
            __builtin_amdgcn_readlane(__float_as_int(lm), 63));
        // ---- first (smallest) global index in this thread matching V ----
        unsigned cand = 0xFFFFFFFFu;
#pragma unroll
        for (int j = PPT - 1; j >= 0; --j)
            cand = (d2[j] == V) ? (unsigned)(t + j * FPS_T) : cand;
        // ---- wave min index ----
        cand = wave_min_u32(cand);
        // ---- cross-wave combine: one LDS atomic per wave ----
        if ((t & 63) == 63) {
            const unsigned long long key =
                ((unsigned long long)(unsigned)__float_as_int(V) << 32) |
                (unsigned long long)(~cand);
            atomicMax(&s_key[m % 3], key);
        }
        if (t == 0) s_key[(m + 1) % 3] = 0ull;   // reset slot for iter m+1
        __syncthreads();
        const unsigned long long key = s_key[m % 3];
        const int bi = (int)(~(unsigned)key);
        if (t == 0) s_oidx[m] = bi;
        qx = s_Px[bi]; qy = s_Py[bi]; qz = s_Pz[bi];   // broadcast LDS reads
    }
    __syncthreads();

    // ---- flush outputs ----
    float* __restrict__ o2 = out_p2 + (size_t)b * Mn * 3;
    float* __restrict__ oi = out_idxf + (size_t)b * Mn;
    for (int i = t; i < Mn; i += FPS_T) {
        const int bi = s_oidx[i];
        oi[i] = (float)bi;
        o2[i * 3 + 0] = s_Px[bi];
        o2[i * 3 + 1] = s_Py[bi];
        o2[i * 3 + 2] = s_Pz[bi];
    }
}

// ---------------------------------------------------------------------------
// kNN + feature mean (unchanged from round 1 — passed).
// ---------------------------------------------------------------------------
#define KNN_WPB 4
__global__ __launch_bounds__(64 * KNN_WPB) void knn_mean_kernel(
    const float* __restrict__ p1,
    const float* __restrict__ x,
    const float* __restrict__ p2,
    float* __restrict__ y)
{
    const int lane = threadIdx.x & 63;
    const int wid  = threadIdx.x >> 6;
    const int q    = blockIdx.x * KNN_WPB + wid;    // 0 .. B*M-1
    const int b    = q >> 11;                        // q / Mn  (Mn = 2048)
    const float* __restrict__ P = p1 + (size_t)b * (Nn * 3);

    const float qx = p2[(size_t)q * 3 + 0];
    const float qy = p2[(size_t)q * 3 + 1];
    const float qz = p2[(size_t)q * 3 + 2];
    const float qq = __fadd_rn(
        __fadd_rn(__fmul_rn(qx, qx), __fmul_rn(qy, qy)), __fmul_rn(qz, qz));

    float slotv = __int_as_float(0x7f800000);
    int   sloti = 0x7fffffff;
    float thr   = __int_as_float(0x7f800000);
    int   thri  = 0x7fffffff;

    for (int c = 0; c < Nn / 64; ++c) {
        const int g = c * 64 + lane;
        const float ax = P[g * 3 + 0];
        const float ay = P[g * 3 + 1];
        const float az = P[g * 3 + 2];
        const float pp = __fadd_rn(
            __fadd_rn(__fmul_rn(ax, ax), __fmul_rn(ay, ay)), __fmul_rn(az, az));
        const float dot = __fmaf_rn(az, qz, __fmaf_rn(ay, qy, __fmul_rn(ax, qx)));
        const float d = __fsub_rn(__fadd_rn(qq, pp), __fmul_rn(2.0f, dot));
        const bool pass = (d < thr) || (d == thr && g < thri);
        unsigned long long ball = __ballot(pass);
        while (ball) {
            const int src = __builtin_ctzll(ball);
            ball &= ball - 1ull;
            const float v  = __shfl(d, src);
            const int   vi = __shfl(g, src);
            const float upv = __shfl_up(slotv, 1);
            const int   upi = __shfl_up(sloti, 1);
            const bool beforeme = (v < slotv) || (v == slotv && vi < sloti);
            bool beforeup = (v < upv) || (v == upv && vi < upi);
            if (lane == 0) beforeup = false;
            if (beforeme) {
                slotv = beforeup ? upv : v;
                sloti = beforeup ? upi : vi;
            }
            thr  = __shfl(slotv, 15);
            thri = __shfl(sloti, 15);
        }
    }

    float acc = 0.0f;
    const float* __restrict__ xb = x + (size_t)b * Nn * Cn;
#pragma unroll
    for (int s = 0; s < Kn; ++s) {
        const int ni = __shfl(sloti, s);
        acc = __fadd_rn(acc, xb[(size_t)ni * Cn + lane]);   // lane == channel
    }
    y[(size_t)q * Cn + lane] = __fmul_rn(acc, 0.0625f);
}

// ---------------------------------------------------------------------------
extern "C" void kernel_launch(void* const* d_in, const int* in_sizes, int n_in,
                              void* d_out, int out_size, void* d_ws, size_t ws_size,
                              hipStream_t stream) {
    const float* p1 = (const float*)d_in[0];
    const float* x  = (const float*)d_in[1];

    float* y    = (float*)d_out;                       // (B, M, C)
    float* p2   = y    + (size_t)Bn * Mn * Cn;         // (B, M, 3)
    float* idxf = p2   + (size_t)Bn * Mn * 3;          // (B, M) as float

    fps_kernel<<<Bn, FPS_T, 0, stream>>>(p1, p2, idxf);
    knn_mean_kernel<<<(Bn * Mn) / KNN_WPB, 64 * KNN_WPB, 0, stream>>>(p1, x, p2, y);
}

// Round 5
// 2115.788 us; speedup vs baseline: 1.3970x; 1.0028x over previous
//
#include <hip/hip_runtime.h>

#define Bn 8
#define Nn 8192
#define Cn 64
#define Mn 2048
#define Kn 16
#define FPS_T 512
#define PPT (Nn / FPS_T)     // 16 points/thread
#define NPAIR (PPT / 2)      // 8 float2 pairs/thread

typedef float f32x2 __attribute__((ext_vector_type(2)));
typedef unsigned long long u64;

// ---- DPP wave-64 reductions (rocPRIM gfx9 pattern), result valid in lane 63.
template <int CTRL, int RMASK>
__device__ __forceinline__ float dpp_max_step(float v) {
    int mv = __builtin_amdgcn_update_dpp(__float_as_int(v), __float_as_int(v),
                                         CTRL, RMASK, 0xF, false);
    return fmaxf(v, __int_as_float(mv));
}
template <int CTRL, int RMASK>
__device__ __forceinline__ unsigned dpp_min_step(unsigned v) {
    unsigned mv = (unsigned)__builtin_amdgcn_update_dpp((int)v, (int)v,
                                                        CTRL, RMASK, 0xF, false);
    return (mv < v) ? mv : v;
}
__device__ __forceinline__ float wave_max_f32(float v) {
    v = dpp_max_step<0x111, 0xF>(v);   // row_shr:1
    v = dpp_max_step<0x112, 0xF>(v);   // row_shr:2
    v = dpp_max_step<0x114, 0xF>(v);   // row_shr:4
    v = dpp_max_step<0x118, 0xF>(v);   // row_shr:8
    v = dpp_max_step<0x142, 0xA>(v);   // row_bcast:15
    v = dpp_max_step<0x143, 0xC>(v);   // row_bcast:31
    return v;                           // lane 63 holds the wave max
}
__device__ __forceinline__ unsigned wave_min_u32(unsigned v) {
    v = dpp_min_step<0x111, 0xF>(v);
    v = dpp_min_step<0x112, 0xF>(v);
    v = dpp_min_step<0x114, 0xF>(v);
    v = dpp_min_step<0x118, 0xF>(v);
    v = dpp_min_step<0x142, 0xA>(v);
    v = dpp_min_step<0x143, 0xC>(v);
    return v;                           // lane 63 holds the wave min
}
__device__ __forceinline__ u64 u64max(u64 a, u64 b) { return a > b ? a : b; }

// ---------------------------------------------------------------------------
// FPS: one block/batch, 512 threads, 16 pts/thread in registers (as 8 f32x2
// pairs -> packed dual-FP32 VALU). One barrier/iter. Cross-wave argmax via
// per-wave packed (valbits<<32 | ~idx) keys in a double-buffered LDS slot
// array, max-reduced in registers by every thread. Distance arithmetic
// bit-identical to XLA (p + (-q), separate mul/add, no FMA contraction).
// ---------------------------------------------------------------------------
__global__ __launch_bounds__(FPS_T) void fps_kernel(
    const float* __restrict__ p1,
    float* __restrict__ out_p2,
    float* __restrict__ out_idxf)
{
#pragma clang fp contract(off)
    __shared__ float s_Px[Nn], s_Py[Nn], s_Pz[Nn];      // 96 KB
    __shared__ u64 s_wkey[2][8];
    __shared__ int s_oidx[Mn];                           // 8 KB

    const int b = blockIdx.x;
    const int t = threadIdx.x;
    const int w = t >> 6;
    const float* __restrict__ P = p1 + (size_t)b * (Nn * 3);

    f32x2 px2[NPAIR], py2[NPAIR], pz2[NPAIR], d2v[NPAIR];
#pragma unroll
    for (int j = 0; j < PPT; ++j) {
        const int g = t + j * FPS_T;
        const float x = P[g * 3 + 0];
        const float y = P[g * 3 + 1];
        const float z = P[g * 3 + 2];
        const int k = j >> 1;
        if ((j & 1) == 0) { px2[k].x = x; py2[k].x = y; pz2[k].x = z; d2v[k].x = __int_as_float(0x7f800000); }
        else              { px2[k].y = x; py2[k].y = y; pz2[k].y = z; d2v[k].y = __int_as_float(0x7f800000); }
        s_Px[g] = x; s_Py[g] = y; s_Pz[g] = z;
    }
    if (t == 0) s_oidx[0] = 0;
    __syncthreads();

    float qx = s_Px[0], qy = s_Py[0], qz = s_Pz[0];

    for (int m = 1; m < Mn; ++m) {
#pragma clang fp contract(off)
        // ---- exact distance update + per-thread max (value only) ----
        const f32x2 nqx = { -qx, -qx };
        const f32x2 nqy = { -qy, -qy };
        const f32x2 nqz = { -qz, -qz };
        float lm = -1.0f;
#pragma unroll
        for (int k = 0; k < NPAIR; ++k) {
            const f32x2 dx = px2[k] + nqx;            // p - q  (exact: x+(-y))
            const f32x2 dy = py2[k] + nqy;
            const f32x2 dz = pz2[k] + nqz;
            const f32x2 mx = dx * dx;
            const f32x2 my = dy * dy;
            const f32x2 mz = dz * dz;
            const f32x2 s  = (mx + my) + mz;          // XLA order, no FMA
            const float nlo = fminf(d2v[k].x, s.x);
            const float nhi = fminf(d2v[k].y, s.y);
            d2v[k].x = nlo;
            d2v[k].y = nhi;
            lm = fmaxf(lm, nlo);
            lm = fmaxf(lm, nhi);
        }
        // ---- wave max value ----
        lm = wave_max_f32(lm);
        const float V = __int_as_float(
            __builtin_amdgcn_readlane(__float_as_int(lm), 63));
        // ---- first (smallest) global index in this thread matching V ----
        unsigned cand = 0xFFFFFFFFu;
#pragma unroll
        for (int k = NPAIR - 1; k >= 0; --k) {        // descending g order
            const unsigned ghi = (unsigned)(t + (2 * k + 1) * FPS_T);
            const unsigned glo = (unsigned)(t + (2 * k) * FPS_T);
            cand = (d2v[k].y == V) ? ghi : cand;
            cand = (d2v[k].x == V) ? glo : cand;
        }
        // ---- wave min index ----
        cand = wave_min_u32(cand);
        // ---- publish per-wave key; double-buffered slots, one barrier ----
        if ((t & 63) == 63) {
            const u64 key = ((u64)(unsigned)__float_as_int(V) << 32) |
                            (u64)(~cand);
            s_wkey[m & 1][w] = key;
        }
        __syncthreads();
        const u64* __restrict__ K = s_wkey[m & 1];
        const u64 a0 = u64max(K[0], K[1]);
        const u64 a1 = u64max(K[2], K[3]);
        const u64 a2 = u64max(K[4], K[5]);
        const u64 a3 = u64max(K[6], K[7]);
        const u64 kk = u64max(u64max(a0, a1), u64max(a2, a3));
        const int bi = (int)(~(unsigned)kk);
        if (t == 0) s_oidx[m] = bi;
        qx = s_Px[bi]; qy = s_Py[bi]; qz = s_Pz[bi];   // broadcast LDS reads
    }
    __syncthreads();

    // ---- flush outputs ----
    float* __restrict__ o2 = out_p2 + (size_t)b * Mn * 3;
    float* __restrict__ oi = out_idxf + (size_t)b * Mn;
    for (int i = t; i < Mn; i += FPS_T) {
        const int bi = s_oidx[i];
        oi[i] = (float)bi;
        o2[i * 3 + 0] = s_Px[bi];
        o2[i * 3 + 1] = s_Py[bi];
        o2[i * 3 + 2] = s_Pz[bi];
    }
}

// ---------------------------------------------------------------------------
// kNN + feature mean (unchanged — passed in rounds 1 and 4).
// ---------------------------------------------------------------------------
#define KNN_WPB 4
__global__ __launch_bounds__(64 * KNN_WPB) void knn_mean_kernel(
    const float* __restrict__ p1,
    const float* __restrict__ x,
    const float* __restrict__ p2,
    float* __restrict__ y)
{
    const int lane = threadIdx.x & 63;
    const int wid  = threadIdx.x >> 6;
    const int q    = blockIdx.x * KNN_WPB + wid;    // 0 .. B*M-1
    const int b    = q >> 11;                        // q / Mn  (Mn = 2048)
    const float* __restrict__ P = p1 + (size_t)b * (Nn * 3);

    const float qx = p2[(size_t)q * 3 + 0];
    const float qy = p2[(size_t)q * 3 + 1];
    const float qz = p2[(size_t)q * 3 + 2];
    const float qq = __fadd_rn(
        __fadd_rn(__fmul_rn(qx, qx), __fmul_rn(qy, qy)), __fmul_rn(qz, qz));

    float slotv = __int_as_float(0x7f800000);
    int   sloti = 0x7fffffff;
    float thr   = __int_as_float(0x7f800000);
    int   thri  = 0x7fffffff;

    for (int c = 0; c < Nn / 64; ++c) {
        const int g = c * 64 + lane;
        const float ax = P[g * 3 + 0];
        const float ay = P[g * 3 + 1];
        const float az = P[g * 3 + 2];
        const float pp = __fadd_rn(
            __fadd_rn(__fmul_rn(ax, ax), __fmul_rn(ay, ay)), __fmul_rn(az, az));
        const float dot = __fmaf_rn(az, qz, __fmaf_rn(ay, qy, __fmul_rn(ax, qx)));
        const float d = __fsub_rn(__fadd_rn(qq, pp), __fmul_rn(2.0f, dot));
        const bool pass = (d < thr) || (d == thr && g < thri);
        unsigned long long ball = __ballot(pass);
        while (ball) {
            const int src = __builtin_ctzll(ball);
            ball &= ball - 1ull;
            const float v  = __shfl(d, src);
            const int   vi = __shfl(g, src);
            const float upv = __shfl_up(slotv, 1);
            const int   upi = __shfl_up(sloti, 1);
            const bool beforeme = (v < slotv) || (v == slotv && vi < sloti);
            bool beforeup = (v < upv) || (v == upv && vi < upi);
            if (lane == 0) beforeup = false;
            if (beforeme) {
                slotv = beforeup ? upv : v;
                sloti = beforeup ? upi : vi;
            }
            thr  = __shfl(slotv, 15);
            thri = __shfl(sloti, 15);
        }
    }

    float acc = 0.0f;
    const float* __restrict__ xb = x + (size_t)b * Nn * Cn;
#pragma unroll
    for (int s = 0; s < Kn; ++s) {
        const int ni = __shfl(sloti, s);
        acc = __fadd_rn(acc, xb[(size_t)ni * Cn + lane]);   // lane == channel
    }
    y[(size_t)q * Cn + lane] = __fmul_rn(acc, 0.0625f);
}

// ---------------------------------------------------------------------------
extern "C" void kernel_launch(void* const* d_in, const int* in_sizes, int n_in,
                              void* d_out, int out_size, void* d_ws, size_t ws_size,
                              hipStream_t stream) {
    const float* p1 = (const float*)d_in[0];
    const float* x  = (const float*)d_in[1];

    float* y    = (float*)d_out;                       // (B, M, C)
    float* p2   = y    + (size_t)Bn * Mn * Cn;         // (B, M, 3)
    float* idxf = p2   + (size_t)Bn * Mn * 3;          // (B, M) as float

    fps_kernel<<<Bn, FPS_T, 0, stream>>>(p1, p2, idxf);
    knn_mean_kernel<<<(Bn * Mn) / KNN_WPB, 64 * KNN_WPB, 0, stream>>>(p1, x, p2, y);
}